// Round 4
// baseline (208.684 us; speedup 1.0000x reference)
//
#include <hip/hip_runtime.h>

#define N_NODES 50000
#define N_EDGES 1600000
#define IN_DIM  256
#define OUT_D   128   // N_HEADS * OUT_DIM
#define NEG_SLOPE 0.2f
#define NBIN 256      // coarse dst bins
#define BINW 196      // nodes per coarse bin (256*196 = 50176 >= N_NODES)
#define CAP  8192     // per-coarse-bin edge capacity (mean 6270, +24 sigma)
#define NFINE 8       // fine sub-bins per coarse bin
#define FBINW 25      // nodes per fine bin (7*25 + 21 = 196)
#define LCAP 1152     // aggB lcsr capacity (fine mean 800, +12 sigma)
#define GEMM_BLOCKS 391   // (N_NODES+127)/128
#define BINA_BLOCKS 196   // (N_EDGES+8191)/8192

typedef unsigned short ushort_t;
typedef short bf16x8 __attribute__((ext_vector_type(8)));
typedef float f32x4 __attribute__((ext_vector_type(4)));

__device__ __forceinline__ ushort_t f2bf(float f) {
    unsigned u = __float_as_uint(f);
    u = (u + 0x7FFF + ((u >> 16) & 1)) >> 16;   // RNE
    return (ushort_t)u;
}

// ---------------------------------------------------------------------------
// K0: W fp32 [256][128] -> wt bf16 [n][k] (plain transpose; gemm reads B from L2).
__global__ __launch_bounds__(256) void wprep_kernel(const float* __restrict__ W,
                                                    ushort_t* __restrict__ wt) {
    int i0 = (blockIdx.x * 256 + threadIdx.x) * 4;   // grid 32 -> covers 32768
    f32x4 v = *(const f32x4*)(W + i0);
    int k = i0 >> 7;
    int n0 = i0 & 127;
#pragma unroll
    for (int j = 0; j < 4; ++j)
        wt[((n0 + j) << 8) + k] = f2bf(v[j]);
}

// ---------------------------------------------------------------------------
// K1 (fused): blocks [0,391) do the MFMA gemm (no LDS -> 4 blocks/CU);
//             blocks [391,587) do coarse-256 binning.
__global__ __launch_bounds__(256, 4) void gemmbin_kernel(
        const float* __restrict__ h, const ushort_t* __restrict__ wt,
        const float* __restrict__ a,
        const int* __restrict__ src, const int* __restrict__ dst,
        ushort_t* __restrict__ hp, float* __restrict__ asrc,
        float* __restrict__ adst,
        int* __restrict__ tail, unsigned* __restrict__ binbuf) {
    int t = threadIdx.x;
    if (blockIdx.x < GEMM_BLOCKS) {
        // ----- gemm branch (B operand streamed from L2-resident wt) -----
        int wave = t >> 6, lane = t & 63;
        int l15 = lane & 15, quad = lane >> 4;
        int rowbase = blockIdx.x * 128 + wave * 16;

        f32x4 acc[2][8] = {};
#pragma unroll
        for (int ks = 0; ks < 8; ++ks) {
            bf16x8 af[2];
#pragma unroll
            for (int rt = 0; rt < 2; ++rt) {
                int arow = rowbase + rt * 64 + l15;
                if (arow >= N_NODES) arow = N_NODES - 1;
                const float* ap = h + (size_t)arow * IN_DIM + quad * 8 + ks * 32;
                f32x4 lo = *(const f32x4*)ap;
                f32x4 hi = *(const f32x4*)(ap + 4);
#pragma unroll
                for (int j = 0; j < 4; ++j) {
                    af[rt][j]     = (short)f2bf(lo[j]);
                    af[rt][4 + j] = (short)f2bf(hi[j]);
                }
            }
#pragma unroll
            for (int tn = 0; tn < 8; ++tn) {
                int n = tn * 16 + l15;
                bf16x8 bfr = *(const bf16x8*)(wt + (n << 8) + ks * 32 + quad * 8);
                acc[0][tn] = __builtin_amdgcn_mfma_f32_16x16x32_bf16(af[0], bfr, acc[0][tn], 0, 0, 0);
                acc[1][tn] = __builtin_amdgcn_mfma_f32_16x16x32_bf16(af[1], bfr, acc[1][tn], 0, 0, 0);
            }
        }

        float aS[8], aD[8];
#pragma unroll
        for (int tn = 0; tn < 8; ++tn) {
            int col = tn * 16 + l15;
            int dd = col & 31, hh = col >> 5;
            aS[tn] = a[dd * 4 + hh];
            aD[tn] = a[(32 + dd) * 4 + hh];
        }

#pragma unroll
        for (int rt = 0; rt < 2; ++rt)
#pragma unroll
            for (int r = 0; r < 4; ++r) {
                int row = rowbase + rt * 64 + quad * 4 + r;
                float pS[4] = {0.f, 0.f, 0.f, 0.f}, pD[4] = {0.f, 0.f, 0.f, 0.f};
#pragma unroll
                for (int tn = 0; tn < 8; ++tn) {
                    float v = acc[rt][tn][r];
                    pS[tn >> 1] += v * aS[tn];
                    pD[tn >> 1] += v * aD[tn];
                }
#pragma unroll
                for (int o = 1; o < 16; o <<= 1) {
#pragma unroll
                    for (int hh = 0; hh < 4; ++hh) {
                        pS[hh] += __shfl_xor(pS[hh], o, 16);
                        pD[hh] += __shfl_xor(pD[hh], o, 16);
                    }
                }
                if (row < N_NODES) {
                    if (l15 == 0) { f32x4 v = {pS[0], pS[1], pS[2], pS[3]}; *(f32x4*)(asrc + row * 4) = v; }
                    if (l15 == 1) { f32x4 v = {pD[0], pD[1], pD[2], pD[3]}; *(f32x4*)(adst + row * 4) = v; }
                }
            }

#pragma unroll
        for (int rt = 0; rt < 2; ++rt)
#pragma unroll
            for (int tn = 0; tn < 8; ++tn) {
                int col = tn * 16 + l15;
#pragma unroll
                for (int r = 0; r < 4; ++r) {
                    int row = rowbase + rt * 64 + quad * 4 + r;
                    if (row < N_NODES) hp[(size_t)row * OUT_D + col] = f2bf(acc[rt][tn][r]);
                }
            }
    } else {
        // ----- binA branch: coarse 256-bin scatter -----
        __shared__ unsigned stage[8192];    // 32 KB
        __shared__ int cnt[256], lcnt[256], lbase[256], gbase[256], sc[256];
        int bid = blockIdx.x - GEMM_BLOCKS;
        cnt[t] = 0; lcnt[t] = 0;
        __syncthreads();

        int blockbase = bid * 8192;
        int n = min(8192, N_EDGES - blockbase);
        int e0 = blockbase + t * 32;
        int d[32], s[32];
#pragma unroll
        for (int q = 0; q < 8; ++q) {
            if (t * 32 + q * 4 + 4 <= n) {
                int4 dv = *(const int4*)(dst + e0 + q * 4);
                int4 sv = *(const int4*)(src + e0 + q * 4);
                d[q*4+0]=dv.x; d[q*4+1]=dv.y; d[q*4+2]=dv.z; d[q*4+3]=dv.w;
                s[q*4+0]=sv.x; s[q*4+1]=sv.y; s[q*4+2]=sv.z; s[q*4+3]=sv.w;
            } else {
#pragma unroll
                for (int r = 0; r < 4; ++r) {
                    int g = t * 32 + q * 4 + r;
                    d[q*4+r] = (g < n) ? dst[e0 + q*4 + r] : -1;
                    s[q*4+r] = (g < n) ? src[e0 + q*4 + r] : 0;
                }
            }
        }
#pragma unroll
        for (int j = 0; j < 32; ++j)
            if (d[j] >= 0) atomicAdd(&cnt[(unsigned)d[j] / BINW], 1);
        __syncthreads();
        gbase[t] = atomicAdd(&tail[t], cnt[t]);     // the ONLY global atomics
        sc[t] = cnt[t]; __syncthreads();
#pragma unroll
        for (int off = 1; off < 256; off <<= 1) {
            int v = (t >= off) ? sc[t - off] : 0;
            __syncthreads();
            sc[t] += v;
            __syncthreads();
        }
        lbase[t] = sc[t] - cnt[t];
        __syncthreads();
#pragma unroll
        for (int j = 0; j < 32; ++j) {
            if (d[j] >= 0) {
                unsigned p = (unsigned)d[j] / BINW;
                unsigned ldst = (unsigned)d[j] - p * BINW;
                int pos = lbase[p] + atomicAdd(&lcnt[p], 1);
                stage[pos] = (unsigned)s[j] | (ldst << 16) | (p << 24);
            }
        }
        __syncthreads();
        for (int i = t; i < n; i += 256) {
            unsigned v = stage[i];
            unsigned p = v >> 24;
            int pos = gbase[p] + (i - lbase[p]);
            if (pos < CAP) binbuf[(size_t)p * CAP + pos] = v & 0xFFFFFFu;
        }
    }
}

// ---------------------------------------------------------------------------
// K4 (binB): one block per coarse bin. Partitions the bin's entries IN PLACE
//   into 8 contiguous fine sub-bins via LDS-atomic ranks (order within a fine
//   bin is irrelevant); rewrites ldst to fine-local; emits fbase/fcnt.
__global__ __launch_bounds__(256) void binB_kernel(const int* __restrict__ tail,
                                                   unsigned* __restrict__ binbuf,
                                                   int* __restrict__ fbase,
                                                   int* __restrict__ fcnt) {
    int b = blockIdx.x, t = threadIdx.x;
    __shared__ unsigned stg[CAP];            // 32 KB
    __shared__ int hist[NFINE], jcur[NFINE];
    int count = min(tail[b], CAP);
    unsigned* buf = binbuf + (size_t)b * CAP;

    if (t < NFINE) hist[t] = 0;
    __syncthreads();
    for (int i = t; i < count; i += 256) {
        int ldst = (int)(buf[i] >> 16);
        int j = (ldst * 5243) >> 17;         // ldst/25 for ldst in [0,196)
        atomicAdd(&hist[j], 1);
    }
    __syncthreads();
    if (t == 0) {
        int r = 0;
#pragma unroll
        for (int jj = 0; jj < NFINE; ++jj) {
            jcur[jj] = r;
            fbase[b * NFINE + jj] = r;
            fcnt [b * NFINE + jj] = hist[jj];
            r += hist[jj];
        }
    }
    __syncthreads();
    for (int i = t; i < count; i += 256) {
        unsigned v = buf[i];
        int ldst = (int)(v >> 16);
        int j = (ldst * 5243) >> 17;
        int p = atomicAdd(&jcur[j], 1);
        stg[p] = (v & 0xFFFFu) | ((unsigned)(ldst - j * FBINW) << 16);
    }
    __syncthreads();
    for (int i = t; i < count; i += 256) buf[i] = stg[i];
}

// ---------------------------------------------------------------------------
// K6 (aggB): one block per fine bin (grid 2048 = 8 blocks/CU). CSR build in
//   LDS, then a software-PIPELINED node loop: while node i's hp gather +
//   shfl epilogue run, node i+1's lcsr/asrc/adst loads are already in flight.
//   __launch_bounds__(256,8) caps VGPR at 64 to keep 8 blocks/CU.
__global__ __launch_bounds__(256, 8) void aggB_kernel(const unsigned* __restrict__ binbuf,
                                                      const int* __restrict__ fbase,
                                                      const int* __restrict__ fcnt,
                                                      const float* __restrict__ asrc,
                                                      const float* __restrict__ adst,
                                                      const ushort_t* __restrict__ hp,
                                                      float* __restrict__ out) {
    int bid = blockIdx.x;
    int b = bid >> 3, fj = bid & 7;
    __shared__ ushort_t lcsr[LCAP];                // 2.3 KB
    __shared__ int cnt[32], sc[32], excl[32], lcur[32];
    __shared__ int   s_i[4][64];
    __shared__ f32x4 s_p[4][64];
    int t = threadIdx.x;
    int count = min(fcnt[bid], LCAP);
    const unsigned* buf = binbuf + (size_t)b * CAP + fbase[bid];
    int dbase = b * BINW + fj * FBINW;
    int nd = min(FBINW, BINW - fj * FBINW);        // 25, or 21 for fj==7

    if (t < 32) cnt[t] = 0;
    __syncthreads();
    for (int i = t; i < count; i += 256)
        atomicAdd(&cnt[(buf[i] >> 16) & 31], 1);
    __syncthreads();
    if (t < 64) {                                   // 32-wide scan in wave 0
        int v = (t < 32) ? cnt[t] : 0;
#pragma unroll
        for (int off = 1; off < 32; off <<= 1) {
            int u = __shfl_up(v, off, 64);
            if (t >= off) v += u;
        }
        if (t < 32) { sc[t] = v; excl[t] = v - cnt[t]; lcur[t] = v - cnt[t]; }
    }
    __syncthreads();
    for (int i = t; i < count; i += 256) {
        unsigned v = buf[i];
        int ld = (v >> 16) & 31;
        int pos = atomicAdd(&lcur[ld], 1);
        lcsr[pos] = (ushort_t)(v & 0xFFFF);
    }
    __syncthreads();

    int wave = t >> 6, lane = t & 63;
    int l15 = lane & 15, grp = lane >> 4;
    int hd = l15 >> 2;

    // ---- prologue: prefetch first node's first chunk into registers ----
    int d_c = 0, s0_c = 0, s1_c = 0, s_c = 0;
    f32x4 ad_c = (f32x4){0.f, 0.f, 0.f, 0.f}, as_c = (f32x4){0.f, 0.f, 0.f, 0.f};
    if (wave < nd) {
        d_c = dbase + wave;
        s0_c = excl[wave]; s1_c = sc[wave];
        if (d_c < N_NODES) ad_c = *(const f32x4*)(adst + d_c * 4);
        int e = s0_c + lane;
        s_c = (e < s1_c) ? (int)lcsr[e] : 0;
        as_c = *(const f32x4*)(asrc + s_c * 4);
    }

    for (int ld = wave; ld < nd; ld += 4) {
        int d = d_c, s0 = s0_c, s1 = s1_c, scur = s_c;
        f32x4 ad = ad_c, as0 = as_c;

        float sum[4] = {0.f, 0.f, 0.f, 0.f};
        f32x4 accA = {0.f, 0.f, 0.f, 0.f}, accB = {0.f, 0.f, 0.f, 0.f};

        // phase 1 (first chunk) from prefetched registers
        {
            bool ok = (s0 + lane) < s1;
            f32x4 p4 = {0.f, 0.f, 0.f, 0.f};
            if (ok) {
#pragma unroll
                for (int hh = 0; hh < 4; ++hh) {
                    float v = as0[hh] + ad[hh];
                    v = v > 0.f ? v : NEG_SLOPE * v;
                    v = fminf(v, 80.f);
                    float p = __expf(v);
                    p4[hh] = p;
                    sum[hh] += p;
                }
            }
            s_i[wave][lane] = scur;
            s_p[wave][lane] = p4;
        }
        __builtin_amdgcn_wave_barrier();

        // ---- prefetch NEXT node's first chunk (overlaps gather+epilogue) ----
        int ldn = ld + 4;
        d_c = 0; s0_c = 0; s1_c = 0; s_c = 0;
        ad_c = (f32x4){0.f, 0.f, 0.f, 0.f}; as_c = (f32x4){0.f, 0.f, 0.f, 0.f};
        if (ldn < nd) {
            d_c = dbase + ldn;
            s0_c = excl[ldn]; s1_c = sc[ldn];
            if (d_c < N_NODES) ad_c = *(const f32x4*)(adst + d_c * 4);
            int e = s0_c + lane;
            s_c = (e < s1_c) ? (int)lcsr[e] : 0;
            as_c = *(const f32x4*)(asrc + s_c * 4);
        }

        // phase 2 (first chunk): hp gather + accumulate
        int n1 = min(64, s1 - s0);
        if (n1 > 0) {
            int iters = (n1 + 3) >> 2;
#pragma unroll 2
            for (int it = 0; it < iters; ++it) {
                int ei = it * 4 + grp;
                int se = s_i[wave][ei];
                float w = s_p[wave][ei][hd];
                const char* rp = (const char*)hp + ((size_t)se << 8) + l15 * 16;
                uint4 u = *(const uint4*)rp;
                accA[0] += w * __uint_as_float(u.x << 16);
                accA[1] += w * __uint_as_float(u.x & 0xFFFF0000u);
                accA[2] += w * __uint_as_float(u.y << 16);
                accA[3] += w * __uint_as_float(u.y & 0xFFFF0000u);
                accB[0] += w * __uint_as_float(u.z << 16);
                accB[1] += w * __uint_as_float(u.z & 0xFFFF0000u);
                accB[2] += w * __uint_as_float(u.w << 16);
                accB[3] += w * __uint_as_float(u.w & 0xFFFF0000u);
            }
        }
        __builtin_amdgcn_wave_barrier();

        // rare extra chunks (degree > 64): unpipelined original path
        for (int base = s0 + 64; base < s1; base += 64) {
            int n = min(64, s1 - base);
            int e = base + lane;
            bool ok = e < s1;
            int s = ok ? (int)lcsr[e] : 0;
            f32x4 p4 = {0.f, 0.f, 0.f, 0.f};
            if (ok) {
                f32x4 as = *(const f32x4*)(asrc + s * 4);
#pragma unroll
                for (int hh = 0; hh < 4; ++hh) {
                    float v = as[hh] + ad[hh];
                    v = v > 0.f ? v : NEG_SLOPE * v;
                    v = fminf(v, 80.f);
                    float p = __expf(v);
                    p4[hh] = p;
                    sum[hh] += p;
                }
            }
            s_i[wave][lane] = s;
            s_p[wave][lane] = p4;
            __builtin_amdgcn_wave_barrier();
            int iters = (n + 3) >> 2;
#pragma unroll 2
            for (int it = 0; it < iters; ++it) {
                int ei = it * 4 + grp;
                int se = s_i[wave][ei];
                float w = s_p[wave][ei][hd];
                const char* rp = (const char*)hp + ((size_t)se << 8) + l15 * 16;
                uint4 u = *(const uint4*)rp;
                accA[0] += w * __uint_as_float(u.x << 16);
                accA[1] += w * __uint_as_float(u.x & 0xFFFF0000u);
                accA[2] += w * __uint_as_float(u.y << 16);
                accA[3] += w * __uint_as_float(u.y & 0xFFFF0000u);
                accB[0] += w * __uint_as_float(u.z << 16);
                accB[1] += w * __uint_as_float(u.z & 0xFFFF0000u);
                accB[2] += w * __uint_as_float(u.w << 16);
                accB[3] += w * __uint_as_float(u.w & 0xFFFF0000u);
            }
            __builtin_amdgcn_wave_barrier();
        }

        // epilogue: reduce + write (overlaps next node's in-flight loads)
#pragma unroll
        for (int o = 16; o < 64; o <<= 1) {
#pragma unroll
            for (int q = 0; q < 4; ++q) {
                accA[q] += __shfl_xor(accA[q], o, 64);
                accB[q] += __shfl_xor(accB[q], o, 64);
            }
        }
#pragma unroll
        for (int o = 1; o < 64; o <<= 1) {
#pragma unroll
            for (int hh = 0; hh < 4; ++hh) sum[hh] += __shfl_xor(sum[hh], o, 64);
        }
        if (grp == 0 && d < N_NODES) {
            float den = sum[hd];
            float inv = (den > 0.f) ? 1.f / den : 0.f;
            f32x4 r0, r1;
#pragma unroll
            for (int q = 0; q < 4; ++q) { r0[q] = accA[q] * inv; r1[q] = accB[q] * inv; }
            float* op = out + (size_t)d * OUT_D + l15 * 8;
            *(f32x4*)op = r0;
            *(f32x4*)(op + 4) = r1;
        }
    }
}

// ---------------------------------------------------------------------------
extern "C" void kernel_launch(void* const* d_in, const int* in_sizes, int n_in,
                              void* d_out, int out_size, void* d_ws, size_t ws_size,
                              hipStream_t stream) {
    const float* h   = (const float*)d_in[0];
    const int*   adj = (const int*)d_in[1];
    const float* W   = (const float*)d_in[2];
    const float* a   = (const float*)d_in[3];
    float*       out = (float*)d_out;

    const int* src = adj;
    const int* dst = adj + N_EDGES;

    char* ws = (char*)d_ws;
    size_t o = 0;
    auto alloc = [&](size_t bytes) -> void* {
        void* p = ws + o;
        o = (o + bytes + 255) & ~(size_t)255;
        return p;
    };
    ushort_t* hp     = (ushort_t*)alloc((size_t)N_NODES * OUT_D * 2);  // 12.8 MB bf16
    ushort_t* wt     = (ushort_t*)alloc((size_t)32768 * 2);            // 64 KB
    float*    asrc   = (float*)alloc((size_t)N_NODES * 4 * 4);
    float*    adstp  = (float*)alloc((size_t)N_NODES * 4 * 4);
    int*      tail   = (int*)alloc((size_t)NBIN * 4);
    unsigned* binbuf = (unsigned*)alloc((size_t)NBIN * CAP * 4);       // 8 MB
    int*      fbase  = (int*)alloc((size_t)NBIN * NFINE * 4);          // 8 KB
    int*      fcnt   = (int*)alloc((size_t)NBIN * NFINE * 4);          // 8 KB

    hipMemsetAsync(tail, 0, (size_t)NBIN * 4, stream);

    wprep_kernel<<<32, 256, 0, stream>>>(W, wt);
    gemmbin_kernel<<<GEMM_BLOCKS + BINA_BLOCKS, 256, 0, stream>>>(
        h, wt, a, src, dst, hp, asrc, adstp, tail, binbuf);
    binB_kernel<<<NBIN, 256, 0, stream>>>(tail, binbuf, fbase, fcnt);
    aggB_kernel<<<NBIN * NFINE, 256, 0, stream>>>(binbuf, fbase, fcnt, asrc, adstp, hp, out);
}

// Round 5
// 194.204 us; speedup vs baseline: 1.0746x; 1.0746x over previous
//
#include <hip/hip_runtime.h>

#define N_NODES 50000
#define N_EDGES 1600000
#define IN_DIM  256
#define OUT_D   128   // N_HEADS * OUT_DIM
#define NEG_SLOPE 0.2f
#define NBIN 256      // coarse dst bins
#define BINW 196      // nodes per coarse bin (256*196 = 50176 >= N_NODES)
#define CAP  8192     // per-coarse-bin edge capacity (mean 6270, +24 sigma)
#define NFINE 8       // fine sub-bins per coarse bin
#define FBINW 25      // nodes per fine slice (7*25 + 21 = 196)
#define DCAP 96       // per-node LDS list capacity (deg mean 32, sigma 5.7 -> +11 sigma)
#define GEMM_BLOCKS 391   // (N_NODES+127)/128
#define BINA_BLOCKS 196   // (N_EDGES+8191)/8192

typedef unsigned short ushort_t;
typedef short bf16x8 __attribute__((ext_vector_type(8)));
typedef float f32x4 __attribute__((ext_vector_type(4)));

__device__ __forceinline__ ushort_t f2bf(float f) {
    unsigned u = __float_as_uint(f);
    u = (u + 0x7FFF + ((u >> 16) & 1)) >> 16;   // RNE
    return (ushort_t)u;
}

// ---------------------------------------------------------------------------
// K0: W fp32 [256][128] -> wt bf16 [n][k] (plain transpose; gemm reads B from L2).
__global__ __launch_bounds__(256) void wprep_kernel(const float* __restrict__ W,
                                                    ushort_t* __restrict__ wt) {
    int i0 = (blockIdx.x * 256 + threadIdx.x) * 4;   // grid 32 -> covers 32768
    f32x4 v = *(const f32x4*)(W + i0);
    int k = i0 >> 7;
    int n0 = i0 & 127;
#pragma unroll
    for (int j = 0; j < 4; ++j)
        wt[((n0 + j) << 8) + k] = f2bf(v[j]);
}

// ---------------------------------------------------------------------------
// K1 (fused): blocks [0,391) do the MFMA gemm; blocks [391,587) do coarse-256
//   binning. min-waves=2 (VGPR cap 128): the gemm branch's 64-reg accumulator
//   + fragments needs ~115 VGPR — the old (256,4) bound forced scratch spill.
__global__ __launch_bounds__(256, 2) void gemmbin_kernel(
        const float* __restrict__ h, const ushort_t* __restrict__ wt,
        const float* __restrict__ a,
        const int* __restrict__ src, const int* __restrict__ dst,
        ushort_t* __restrict__ hp, float* __restrict__ asrc,
        float* __restrict__ adst,
        int* __restrict__ tail, unsigned* __restrict__ binbuf) {
    int t = threadIdx.x;
    if (blockIdx.x < GEMM_BLOCKS) {
        // ----- gemm branch (B operand streamed from L2-resident wt) -----
        int wave = t >> 6, lane = t & 63;
        int l15 = lane & 15, quad = lane >> 4;
        int rowbase = blockIdx.x * 128 + wave * 16;

        f32x4 acc[2][8] = {};
#pragma unroll
        for (int ks = 0; ks < 8; ++ks) {
            bf16x8 af[2];
#pragma unroll
            for (int rt = 0; rt < 2; ++rt) {
                int arow = rowbase + rt * 64 + l15;
                if (arow >= N_NODES) arow = N_NODES - 1;
                const float* ap = h + (size_t)arow * IN_DIM + quad * 8 + ks * 32;
                f32x4 lo = *(const f32x4*)ap;
                f32x4 hi = *(const f32x4*)(ap + 4);
#pragma unroll
                for (int j = 0; j < 4; ++j) {
                    af[rt][j]     = (short)f2bf(lo[j]);
                    af[rt][4 + j] = (short)f2bf(hi[j]);
                }
            }
#pragma unroll
            for (int tn = 0; tn < 8; ++tn) {
                int n = tn * 16 + l15;
                bf16x8 bfr = *(const bf16x8*)(wt + (n << 8) + ks * 32 + quad * 8);
                acc[0][tn] = __builtin_amdgcn_mfma_f32_16x16x32_bf16(af[0], bfr, acc[0][tn], 0, 0, 0);
                acc[1][tn] = __builtin_amdgcn_mfma_f32_16x16x32_bf16(af[1], bfr, acc[1][tn], 0, 0, 0);
            }
        }

        float aS[8], aD[8];
#pragma unroll
        for (int tn = 0; tn < 8; ++tn) {
            int col = tn * 16 + l15;
            int dd = col & 31, hh = col >> 5;
            aS[tn] = a[dd * 4 + hh];
            aD[tn] = a[(32 + dd) * 4 + hh];
        }

#pragma unroll
        for (int rt = 0; rt < 2; ++rt)
#pragma unroll
            for (int r = 0; r < 4; ++r) {
                int row = rowbase + rt * 64 + quad * 4 + r;
                float pS[4] = {0.f, 0.f, 0.f, 0.f}, pD[4] = {0.f, 0.f, 0.f, 0.f};
#pragma unroll
                for (int tn = 0; tn < 8; ++tn) {
                    float v = acc[rt][tn][r];
                    pS[tn >> 1] += v * aS[tn];
                    pD[tn >> 1] += v * aD[tn];
                }
#pragma unroll
                for (int o = 1; o < 16; o <<= 1) {
#pragma unroll
                    for (int hh = 0; hh < 4; ++hh) {
                        pS[hh] += __shfl_xor(pS[hh], o, 16);
                        pD[hh] += __shfl_xor(pD[hh], o, 16);
                    }
                }
                if (row < N_NODES) {
                    if (l15 == 0) { f32x4 v = {pS[0], pS[1], pS[2], pS[3]}; *(f32x4*)(asrc + row * 4) = v; }
                    if (l15 == 1) { f32x4 v = {pD[0], pD[1], pD[2], pD[3]}; *(f32x4*)(adst + row * 4) = v; }
                }
            }

#pragma unroll
        for (int rt = 0; rt < 2; ++rt)
#pragma unroll
            for (int tn = 0; tn < 8; ++tn) {
                int col = tn * 16 + l15;
#pragma unroll
                for (int r = 0; r < 4; ++r) {
                    int row = rowbase + rt * 64 + quad * 4 + r;
                    if (row < N_NODES) hp[(size_t)row * OUT_D + col] = f2bf(acc[rt][tn][r]);
                }
            }
    } else {
        // ----- binA branch: coarse 256-bin scatter -----
        __shared__ unsigned stage[8192];    // 32 KB
        __shared__ int cnt[256], lcnt[256], lbase[256], gbase[256], sc[256];
        int bid = blockIdx.x - GEMM_BLOCKS;
        cnt[t] = 0; lcnt[t] = 0;
        __syncthreads();

        int blockbase = bid * 8192;
        int n = min(8192, N_EDGES - blockbase);
        int e0 = blockbase + t * 32;
        int d[32], s[32];
#pragma unroll
        for (int q = 0; q < 8; ++q) {
            if (t * 32 + q * 4 + 4 <= n) {
                int4 dv = *(const int4*)(dst + e0 + q * 4);
                int4 sv = *(const int4*)(src + e0 + q * 4);
                d[q*4+0]=dv.x; d[q*4+1]=dv.y; d[q*4+2]=dv.z; d[q*4+3]=dv.w;
                s[q*4+0]=sv.x; s[q*4+1]=sv.y; s[q*4+2]=sv.z; s[q*4+3]=sv.w;
            } else {
#pragma unroll
                for (int r = 0; r < 4; ++r) {
                    int g = t * 32 + q * 4 + r;
                    d[q*4+r] = (g < n) ? dst[e0 + q*4 + r] : -1;
                    s[q*4+r] = (g < n) ? src[e0 + q*4 + r] : 0;
                }
            }
        }
#pragma unroll
        for (int j = 0; j < 32; ++j)
            if (d[j] >= 0) atomicAdd(&cnt[(unsigned)d[j] / BINW], 1);
        __syncthreads();
        gbase[t] = atomicAdd(&tail[t], cnt[t]);     // the ONLY global atomics
        sc[t] = cnt[t]; __syncthreads();
#pragma unroll
        for (int off = 1; off < 256; off <<= 1) {
            int v = (t >= off) ? sc[t - off] : 0;
            __syncthreads();
            sc[t] += v;
            __syncthreads();
        }
        lbase[t] = sc[t] - cnt[t];
        __syncthreads();
#pragma unroll
        for (int j = 0; j < 32; ++j) {
            if (d[j] >= 0) {
                unsigned p = (unsigned)d[j] / BINW;
                unsigned ldst = (unsigned)d[j] - p * BINW;
                int pos = lbase[p] + atomicAdd(&lcnt[p], 1);
                stage[pos] = (unsigned)s[j] | (ldst << 16) | (p << 24);
            }
        }
        __syncthreads();
        for (int i = t; i < n; i += 256) {
            unsigned v = stage[i];
            unsigned p = v >> 24;
            int pos = gbase[p] + (i - lbase[p]);
            if (pos < CAP) binbuf[(size_t)p * CAP + pos] = v & 0xFFFFFFu;
        }
    }
}

// ---------------------------------------------------------------------------
// K6 (aggB): one block per 25-node fine slice; binB is FUSED: the block scans
//   its coarse bin's entries once and atomic-appends only its slice into
//   fixed-stride per-node LDS lists (25 x 96). Index map b=bid&255, fj=bid>>8
//   puts all 8 slices of coarse bin b on XCD b%8, so the bin's ~25 KB scan
//   is an L2 hit for 7 of the 8 blocks. Gather loop = round-3 structure.
__global__ __launch_bounds__(256) void aggB_kernel(const unsigned* __restrict__ binbuf,
                                                   const int* __restrict__ tail,
                                                   const float* __restrict__ asrc,
                                                   const float* __restrict__ adst,
                                                   const ushort_t* __restrict__ hp,
                                                   float* __restrict__ out) {
    int b  = blockIdx.x & 255;          // coarse bin; XCD(blk)=blk%8=b%8
    int fj = blockIdx.x >> 8;           // fine slice 0..7
    __shared__ ushort_t lcsr[FBINW * DCAP];        // 4.8 KB
    __shared__ int lcur[32];
    __shared__ int   s_i[4][64];
    __shared__ f32x4 s_p[4][64];
    int t = threadIdx.x;
    int count = min(tail[b], CAP);
    const unsigned* buf = binbuf + (size_t)b * CAP;
    int lo = fj * FBINW;
    int nd = min(FBINW, BINW - lo);     // 25, or 21 for fj==7

    if (t < 32) lcur[t] = 0;
    __syncthreads();
    for (int i = t; i < count; i += 256) {
        unsigned v = buf[i];
        int ld = (int)((v >> 16) & 0xFF) - lo;
        if ((unsigned)ld < (unsigned)nd) {
            int pos = atomicAdd(&lcur[ld], 1);
            if (pos < DCAP) lcsr[ld * DCAP + pos] = (ushort_t)(v & 0xFFFF);
        }
    }
    __syncthreads();

    int wave = t >> 6, lane = t & 63;
    int l15 = lane & 15, grp = lane >> 4;
    int hd = l15 >> 2;

    for (int ld = wave; ld < nd; ld += 4) {
        int d = b * BINW + lo + ld;
        if (d >= N_NODES) continue;                 // wave-uniform
        int deg = min(lcur[ld], DCAP);
        const ushort_t* lp = lcsr + ld * DCAP;
        f32x4 ad = *(const f32x4*)(adst + d * 4);
        float sum[4] = {0.f, 0.f, 0.f, 0.f};
        f32x4 accA = {0.f, 0.f, 0.f, 0.f}, accB = {0.f, 0.f, 0.f, 0.f};

        for (int base = 0; base < deg; base += 64) {
            int n = min(64, deg - base);
            int e = base + lane;
            bool ok = e < deg;
            int s = ok ? (int)lp[e] : 0;
            f32x4 p4 = {0.f, 0.f, 0.f, 0.f};
            if (ok) {
                f32x4 as = *(const f32x4*)(asrc + s * 4);
#pragma unroll
                for (int hh = 0; hh < 4; ++hh) {
                    float v = as[hh] + ad[hh];
                    v = v > 0.f ? v : NEG_SLOPE * v;
                    v = fminf(v, 80.f);
                    float p = __expf(v);
                    p4[hh] = p;
                    sum[hh] += p;
                }
            }
            s_i[wave][lane] = s;
            s_p[wave][lane] = p4;
            __builtin_amdgcn_wave_barrier();
            int iters = (n + 3) >> 2;
#pragma unroll 2
            for (int it = 0; it < iters; ++it) {
                int ei = it * 4 + grp;
                int se = s_i[wave][ei];
                float w = s_p[wave][ei][hd];
                const char* rp = (const char*)hp + ((size_t)se << 8) + l15 * 16;
                uint4 u = *(const uint4*)rp;
                accA[0] += w * __uint_as_float(u.x << 16);
                accA[1] += w * __uint_as_float(u.x & 0xFFFF0000u);
                accA[2] += w * __uint_as_float(u.y << 16);
                accA[3] += w * __uint_as_float(u.y & 0xFFFF0000u);
                accB[0] += w * __uint_as_float(u.z << 16);
                accB[1] += w * __uint_as_float(u.z & 0xFFFF0000u);
                accB[2] += w * __uint_as_float(u.w << 16);
                accB[3] += w * __uint_as_float(u.w & 0xFFFF0000u);
            }
            __builtin_amdgcn_wave_barrier();
        }
#pragma unroll
        for (int o = 16; o < 64; o <<= 1) {
#pragma unroll
            for (int q = 0; q < 4; ++q) {
                accA[q] += __shfl_xor(accA[q], o, 64);
                accB[q] += __shfl_xor(accB[q], o, 64);
            }
        }
#pragma unroll
        for (int o = 1; o < 64; o <<= 1) {
#pragma unroll
            for (int hh = 0; hh < 4; ++hh) sum[hh] += __shfl_xor(sum[hh], o, 64);
        }
        if (grp == 0) {
            float den = sum[hd];
            float inv = (den > 0.f) ? 1.f / den : 0.f;
            f32x4 r0, r1;
#pragma unroll
            for (int q = 0; q < 4; ++q) { r0[q] = accA[q] * inv; r1[q] = accB[q] * inv; }
            float* op = out + (size_t)d * OUT_D + l15 * 8;
            *(f32x4*)op = r0;
            *(f32x4*)(op + 4) = r1;
        }
    }
}

// ---------------------------------------------------------------------------
extern "C" void kernel_launch(void* const* d_in, const int* in_sizes, int n_in,
                              void* d_out, int out_size, void* d_ws, size_t ws_size,
                              hipStream_t stream) {
    const float* h   = (const float*)d_in[0];
    const int*   adj = (const int*)d_in[1];
    const float* W   = (const float*)d_in[2];
    const float* a   = (const float*)d_in[3];
    float*       out = (float*)d_out;

    const int* src = adj;
    const int* dst = adj + N_EDGES;

    char* ws = (char*)d_ws;
    size_t o = 0;
    auto alloc = [&](size_t bytes) -> void* {
        void* p = ws + o;
        o = (o + bytes + 255) & ~(size_t)255;
        return p;
    };
    ushort_t* hp     = (ushort_t*)alloc((size_t)N_NODES * OUT_D * 2);  // 12.8 MB bf16
    ushort_t* wt     = (ushort_t*)alloc((size_t)32768 * 2);            // 64 KB
    float*    asrc   = (float*)alloc((size_t)N_NODES * 4 * 4);
    float*    adstp  = (float*)alloc((size_t)N_NODES * 4 * 4);
    int*      tail   = (int*)alloc((size_t)NBIN * 4);
    unsigned* binbuf = (unsigned*)alloc((size_t)NBIN * CAP * 4);       // 8 MB

    hipMemsetAsync(tail, 0, (size_t)NBIN * 4, stream);

    wprep_kernel<<<32, 256, 0, stream>>>(W, wt);
    gemmbin_kernel<<<GEMM_BLOCKS + BINA_BLOCKS, 256, 0, stream>>>(
        h, wt, a, src, dst, hp, asrc, adstp, tail, binbuf);
    aggB_kernel<<<NBIN * NFINE, 256, 0, stream>>>(binbuf, tail, asrc, adstp, hp, out);
}